// Round 12
// baseline (421.708 us; speedup 1.0000x reference)
//
#include <hip/hip_runtime.h>
#include <stdint.h>

#define NROWS 8192
#define DDIM  256
#define K2    512          // [hi | lo] packed per row
#define MARGIN_F 0.2f

typedef short  short8  __attribute__((ext_vector_type(8)));
typedef float  floatx4 __attribute__((ext_vector_type(4)));

// Static device buffers (avoid depending on ws_size).
__device__ unsigned short gA[(size_t)NROWS * K2];   // im split: [hi | lo]
__device__ unsigned short gB[(size_t)NROWS * K2];   // s  split: [hi | lo]
__device__ float    g_diag[NROWS];
__device__ unsigned g_rowcnt[NROWS];
__device__ unsigned g_rowkey[NROWS];
__device__ unsigned g_colcnt[NROWS];
__device__ unsigned g_colkey[NROWS];

__device__ __forceinline__ unsigned short f2bf_rne(float x){
    unsigned u = __float_as_uint(x);
    return (unsigned short)((u + 0x7FFFu + ((u >> 16) & 1u)) >> 16);
}
__device__ __forceinline__ float bf2f(unsigned short h){
    return __uint_as_float(((unsigned)h) << 16);
}
// monotone float -> uint key (order-preserving), so atomicMax works on floats
__device__ __forceinline__ unsigned fkey(float f){
    unsigned u = __float_as_uint(f);
    return (u & 0x80000000u) ? ~u : (u | 0x80000000u);
}
__device__ __forceinline__ float kinv(unsigned k){
    unsigned u = (k & 0x80000000u) ? (k ^ 0x80000000u) : ~k;
    return __uint_as_float(u);
}

// One wave per row: fp32 diag dot, hi/lo bf16 split, stats init.
__global__ __launch_bounds__(256) void prep_kernel(const float* __restrict__ im,
                                                   const float* __restrict__ s){
    const int w    = threadIdx.x >> 6;
    const int lane = threadIdx.x & 63;
    const int row  = blockIdx.x * 4 + w;

    const float4 a = ((const float4*)(im + (size_t)row * DDIM))[lane];
    const float4 b = ((const float4*)(s  + (size_t)row * DDIM))[lane];

    float dp = a.x*b.x + a.y*b.y + a.z*b.z + a.w*b.w;
    #pragma unroll
    for (int m = 1; m < 64; m <<= 1) dp += __shfl_xor(dp, m, 64);
    if (lane == 0){
        g_diag[row]   = dp;
        g_rowcnt[row] = 0u; g_rowkey[row] = 0u;
        g_colcnt[row] = 0u; g_colkey[row] = 0u;
    }

    float av[4] = {a.x, a.y, a.z, a.w};
    float bv[4] = {b.x, b.y, b.z, b.w};
    unsigned short ah[4], al[4], bh[4], bl[4];
    #pragma unroll
    for (int i = 0; i < 4; ++i){
        ah[i] = f2bf_rne(av[i]); al[i] = f2bf_rne(av[i] - bf2f(ah[i]));
        bh[i] = f2bf_rne(bv[i]); bl[i] = f2bf_rne(bv[i] - bf2f(bh[i]));
    }
    const size_t base = (size_t)row * K2 + lane * 4;
    *(ushort4*)&gA[base      ] = make_ushort4(ah[0], ah[1], ah[2], ah[3]);
    *(ushort4*)&gA[base + 256] = make_ushort4(al[0], al[1], al[2], al[3]);
    *(ushort4*)&gB[base      ] = make_ushort4(bh[0], bh[1], bh[2], bh[3]);
    *(ushort4*)&gB[base + 256] = make_ushort4(bl[0], bl[1], bl[2], bl[3]);
}

// ALL-REGISTER GEMM — zero LDS operands, ZERO K-loop barriers.
// 128x128 block, 4 waves x (32 private rows x 128 cols), 16x16x32 bf16 MFMA,
// 8 ks-steps of K=32. All operand fragments loaded global->VGPR in MFMA
// layout (verified R6/R7: absmax 0.0). B-frags are wave-redundant (4x) but
// all 4 waves hit the SAME addresses -> L1/L2 broadcast; vector-load path
// measured ~60 B/cyc/CU from L2 (m56) vs ~10 B/cyc DMA path — and with no
// __syncthreads there is no vmcnt(0) drain to stall on (the R2-R11 plateau).
// Per-XCD bj pinning: bj = (p>>6)*8 + (bid&7) keeps one 131KB B-tile hot in
// each XCD's L2 for 64 consecutive blocks.
// Regs: 16 B-frag short8 (64) + A frags (16) + acc (64 AGPR) + addr ~ 156
// unified <= 170 cap of (256,3) -> 3 blocks/CU, 12 waves.
__global__ __launch_bounds__(256, 3) void gemm_stats_kernel(){
    __shared__ float drow[128];
    __shared__ float dcol[128];

    const int tid = threadIdx.x;
    const int bid = blockIdx.x;
    const int xcd = bid & 7;
    const int p   = bid >> 3;               // 0..511 per-XCD sequence
    const int bi  = p & 63;                 // fast: sweep rows
    const int bj  = (p >> 6) * 8 + xcd;     // slow: 8 bj values per XCD, pinned

    if (tid < 128) drow[tid]       = g_diag[bi * 128 + tid];
    else           dcol[tid - 128] = g_diag[bj * 128 + (tid - 128)];
    __syncthreads();   // the ONLY barrier (diag tables ready; K-loop has none)

    const int w    = tid >> 6, lane = tid & 63;
    const int quad = lane >> 4, l16 = lane & 15;

    floatx4 acc[2][8] = {};

    // fragment bases (MFMA operand layout, verified):
    const unsigned short* AhFrag = gA + (size_t)(bi * 128 + w * 32 + l16) * K2 + quad * 8;
    const unsigned short* AlFrag = AhFrag + 256;
    const unsigned short* BhFrag = gB + (size_t)(bj * 128 + l16) * K2 + quad * 8;
    const unsigned short* BlFrag = BhFrag + 256;

    #pragma unroll 1
    for (int ks = 0; ks < 8; ++ks){
        const size_t ko = (size_t)ks * 32;
        short8 bh[8], bl[8], ah[2], al[2];
        #pragma unroll
        for (int nj = 0; nj < 8; ++nj)
            bh[nj] = *(const short8*)(BhFrag + (size_t)(nj * 16) * K2 + ko);
        #pragma unroll
        for (int nj = 0; nj < 8; ++nj)
            bl[nj] = *(const short8*)(BlFrag + (size_t)(nj * 16) * K2 + ko);
        #pragma unroll
        for (int mi = 0; mi < 2; ++mi){
            ah[mi] = *(const short8*)(AhFrag + (size_t)(mi * 16) * K2 + ko);
            al[mi] = *(const short8*)(AlFrag + (size_t)(mi * 16) * K2 + ko);
        }
        // pass 1: Ah*Bh
        #pragma unroll
        for (int nj = 0; nj < 8; ++nj){
            acc[0][nj] = __builtin_amdgcn_mfma_f32_16x16x32_bf16(ah[0], bh[nj], acc[0][nj], 0, 0, 0);
            acc[1][nj] = __builtin_amdgcn_mfma_f32_16x16x32_bf16(ah[1], bh[nj], acc[1][nj], 0, 0, 0);
        }
        // pass 2: Al*Bh
        #pragma unroll
        for (int nj = 0; nj < 8; ++nj){
            acc[0][nj] = __builtin_amdgcn_mfma_f32_16x16x32_bf16(al[0], bh[nj], acc[0][nj], 0, 0, 0);
            acc[1][nj] = __builtin_amdgcn_mfma_f32_16x16x32_bf16(al[1], bh[nj], acc[1][nj], 0, 0, 0);
        }
        // pass 3: Ah*Bl
        #pragma unroll
        for (int nj = 0; nj < 8; ++nj){
            acc[0][nj] = __builtin_amdgcn_mfma_f32_16x16x32_bf16(ah[0], bl[nj], acc[0][nj], 0, 0, 0);
            acc[1][nj] = __builtin_amdgcn_mfma_f32_16x16x32_bf16(ah[1], bl[nj], acc[1][nj], 0, 0, 0);
        }
    }

    // ---- fused stats epilogue ----
    // C/D layout (verified m89/m91): col = lane&15, row = quad*4 + reg.
    // acc[mi][nj]: row = w*32 + mi*16 + quad*4 + r ; col = nj*16 + l16.
    const int rowbase = bi * 128 + w * 32;
    const int colbase = bj * 128;

    // row stats: each lane holds 8 cols (nj); reduce across l16 lanes.
    #pragma unroll
    for (int mi = 0; mi < 2; ++mi){
        #pragma unroll
        for (int r = 0; r < 4; ++r){
            const int lrow = w * 32 + mi * 16 + quad * 4 + r;
            const int gi   = bi * 128 + lrow;
            const float dv = drow[lrow];
            int cnt = 0; float mx = -3.0e38f;
            #pragma unroll
            for (int nj = 0; nj < 8; ++nj){
                const float v  = acc[mi][nj][r];
                const int   gj = colbase + nj * 16 + l16;
                if (gi != gj){                 // exclude diagonal explicitly
                    cnt += (v < dv) ? 1 : 0;
                    mx = fmaxf(mx, v);
                }
            }
            #pragma unroll
            for (int m = 1; m < 16; m <<= 1){
                cnt += __shfl_xor(cnt, m, 64);
                mx   = fmaxf(mx, __shfl_xor(mx, m, 64));
            }
            if (l16 == 0){
                atomicAdd(&g_rowcnt[gi], (unsigned)cnt);
                atomicMax(&g_rowkey[gi], fkey(mx));
            }
        }
    }
    // col stats: each lane holds 8 rows (mi,r) per nj; reduce across quad lanes.
    #pragma unroll
    for (int nj = 0; nj < 8; ++nj){
        const int lcol = nj * 16 + l16;
        const int gj   = bj * 128 + lcol;
        const float dv = dcol[lcol];
        int cnt = 0; float mx = -3.0e38f;
        #pragma unroll
        for (int mi = 0; mi < 2; ++mi){
            #pragma unroll
            for (int r = 0; r < 4; ++r){
                const float v  = acc[mi][nj][r];
                const int   gi = rowbase + mi * 16 + quad * 4 + r;
                if (gi != gj){
                    cnt += (v < dv) ? 1 : 0;
                    mx = fmaxf(mx, v);
                }
            }
        }
        #pragma unroll
        for (int m = 16; m < 64; m <<= 1){
            cnt += __shfl_xor(cnt, m, 64);
            mx   = fmaxf(mx, __shfl_xor(mx, m, 64));
        }
        if (quad == 0){
            atomicAdd(&g_colcnt[gj], (unsigned)cnt);
            atomicMax(&g_colkey[gj], fkey(mx));
        }
    }
}

__global__ __launch_bounds__(256) void finalize_kernel(float* __restrict__ out){
    __shared__ double red[256];
    double acc = 0.0;
    #pragma unroll
    for (int it = 0; it < NROWS / 256; ++it){
        const int i = it * 256 + threadIdx.x;
        const float d  = g_diag[i];
        const float cs  = fmaxf(MARGIN_F + kinv(g_rowkey[i]) - d, 0.0f) * (1.0f / (float)(g_rowcnt[i] + 1u));
        const float cim = fmaxf(MARGIN_F + kinv(g_colkey[i]) - d, 0.0f) * (1.0f / (float)(g_colcnt[i] + 1u));
        acc += (double)cs + (double)cim;
    }
    red[threadIdx.x] = acc;
    __syncthreads();
    for (int s2 = 128; s2 > 0; s2 >>= 1){
        if (threadIdx.x < s2) red[threadIdx.x] += red[threadIdx.x + s2];
        __syncthreads();
    }
    if (threadIdx.x == 0) out[0] = (float)red[0];
}

extern "C" void kernel_launch(void* const* d_in, const int* in_sizes, int n_in,
                              void* d_out, int out_size, void* d_ws, size_t ws_size,
                              hipStream_t stream){
    const float* im = (const float*)d_in[0];
    const float* s  = (const float*)d_in[1];
    float* out = (float*)d_out;

    prep_kernel<<<NROWS / 4, 256, 0, stream>>>(im, s);
    gemm_stats_kernel<<<4096, 256, 0, stream>>>();
    finalize_kernel<<<1, 256, 0, stream>>>(out);
}

// Round 14
// 282.367 us; speedup vs baseline: 1.4935x; 1.4935x over previous
//
#include <hip/hip_runtime.h>
#include <stdint.h>

#define NROWS 8192
#define DDIM  256
#define K2    512          // [hi | lo] packed per row
#define MARGIN_F 0.2f

typedef short  short8  __attribute__((ext_vector_type(8)));
typedef float  floatx4 __attribute__((ext_vector_type(4)));

// Static device buffers (avoid depending on ws_size).
__device__ unsigned short gA[(size_t)NROWS * K2];   // im split: [hi | lo]
__device__ unsigned short gB[(size_t)NROWS * K2];   // s  split: [hi | lo]
__device__ float    g_diag[NROWS];
__device__ unsigned g_rowcnt[NROWS];
__device__ unsigned g_rowkey[NROWS];
__device__ unsigned g_colcnt[NROWS];
__device__ unsigned g_colkey[NROWS];

__device__ __forceinline__ unsigned short f2bf_rne(float x){
    unsigned u = __float_as_uint(x);
    return (unsigned short)((u + 0x7FFFu + ((u >> 16) & 1u)) >> 16);
}
__device__ __forceinline__ float bf2f(unsigned short h){
    return __uint_as_float(((unsigned)h) << 16);
}
// monotone float -> uint key (order-preserving), so atomicMax works on floats
__device__ __forceinline__ unsigned fkey(float f){
    unsigned u = __float_as_uint(f);
    return (u & 0x80000000u) ? ~u : (u | 0x80000000u);
}
__device__ __forceinline__ float kinv(unsigned k){
    unsigned u = (k & 0x80000000u) ? (k ^ 0x80000000u) : ~k;
    return __uint_as_float(u);
}

__device__ __forceinline__ void load_lds16(const unsigned short* gptr, void* lptr){
    __builtin_amdgcn_global_load_lds(
        (const __attribute__((address_space(1))) unsigned int*)(uintptr_t)gptr,
        (__attribute__((address_space(3))) unsigned int*)(unsigned)(uintptr_t)lptr,
        16, 0, 0);
}

// One wave per row: fp32 diag dot, hi/lo bf16 split, stats init.
__global__ __launch_bounds__(256) void prep_kernel(const float* __restrict__ im,
                                                   const float* __restrict__ s){
    const int w    = threadIdx.x >> 6;
    const int lane = threadIdx.x & 63;
    const int row  = blockIdx.x * 4 + w;

    const float4 a = ((const float4*)(im + (size_t)row * DDIM))[lane];
    const float4 b = ((const float4*)(s  + (size_t)row * DDIM))[lane];

    float dp = a.x*b.x + a.y*b.y + a.z*b.z + a.w*b.w;
    #pragma unroll
    for (int m = 1; m < 64; m <<= 1) dp += __shfl_xor(dp, m, 64);
    if (lane == 0){
        g_diag[row]   = dp;
        g_rowcnt[row] = 0u; g_rowkey[row] = 0u;
        g_colcnt[row] = 0u; g_colkey[row] = 0u;
    }

    float av[4] = {a.x, a.y, a.z, a.w};
    float bv[4] = {b.x, b.y, b.z, b.w};
    unsigned short ah[4], al[4], bh[4], bl[4];
    #pragma unroll
    for (int i = 0; i < 4; ++i){
        ah[i] = f2bf_rne(av[i]); al[i] = f2bf_rne(av[i] - bf2f(ah[i]));
        bh[i] = f2bf_rne(bv[i]); bl[i] = f2bf_rne(bv[i] - bf2f(bh[i]));
    }
    const size_t base = (size_t)row * K2 + lane * 4;
    *(ushort4*)&gA[base      ] = make_ushort4(ah[0], ah[1], ah[2], ah[3]);
    *(ushort4*)&gA[base + 256] = make_ushort4(al[0], al[1], al[2], al[3]);
    *(ushort4*)&gB[base      ] = make_ushort4(bh[0], bh[1], bh[2], bh[3]);
    *(ushort4*)&gB[base + 256] = make_ushort4(bl[0], bl[1], bl[2], bl[3]);
}

// PRODUCER/CONSUMER GEMM — no __syncthreads in the K-loop.
// 128x128 tile, 320 threads: waves 0-3 = compute (R10's verified 32x128 inner
// loop), wave 4 = producer. Producer stages Bh/Bl BK=64 chunks into a
// double-buffered LDS ring via global_load_lds, drains vmcnt ITSELF
// (s_waitcnt(0)), then sets an LDS ready flag; compute waves spin on the flag
// and never execute a vmcnt(0) drain — removing the R2-R12 structural stall.
// Buffer recycling: producer waits for 4 consumer done-posts before reuse.
// A operands stay wave-private registers (MFMA layout, verified), prefetched
// one ks ahead. LDS 66KB -> 2 blocks/CU; launch_bounds(320,2) -> 256-reg cap.
__global__ __launch_bounds__(320, 2) void gemm_stats_kernel(){
    __shared__ unsigned short Bh[2][128 * 64];   // ring: Bh per chunk
    __shared__ unsigned short Bl[2][128 * 64];   // ring: Bl per chunk
    __shared__ float drow[128];
    __shared__ float dcol[128];
    __shared__ int ready4[4];
    __shared__ int consd[4];

    const int tid = threadIdx.x;
    const int bid = blockIdx.x;
    // bid[2:0]->band(XCD), bid[5:3]->row within band, bid[11:6]->column
    const int bi  = (bid & 7) * 8 + ((bid >> 3) & 7);
    const int bj  = bid >> 6;

    if (tid < 128)      drow[tid]       = g_diag[bi * 128 + tid];
    else if (tid < 256) dcol[tid - 128] = g_diag[bj * 128 + (tid - 128)];
    if (tid == 256){
        ready4[0] = ready4[1] = ready4[2] = ready4[3] = 0;
        consd[0]  = consd[1]  = consd[2]  = consd[3]  = 0;
    }
    __syncthreads();   // the ONLY block-wide barrier (flag/table init)

    const int w    = tid >> 6, lane = tid & 63;
    const int quad = lane >> 4, l16 = lane & 15;
    const int sw   = l16 & 7;           // read-side swizzle key

    const unsigned short* Bbase = gB + (size_t)bj * 128 * K2;

    if (w == 4){
        // ================= PRODUCER WAVE =================
        #pragma unroll 1
        for (int c = 0; c < 4; ++c){
            if (c >= 2){
                while (__hip_atomic_load(&consd[c - 2], __ATOMIC_ACQUIRE,
                                         __HIP_MEMORY_SCOPE_WORKGROUP) < 4)
                    __builtin_amdgcn_s_sleep(1);
            }
            unsigned short* Th = Bh[c & 1];
            unsigned short* Tl = Bl[c & 1];
            #pragma unroll
            for (int q = 0; q < 16; ++q){
                const int ch   = q * 64 + lane;           // chunk 0..1023
                const int r    = ch >> 3;                 // tile row
                const int clog = (ch & 7) ^ (r & 7);      // stored -> logical
                const size_t goff = (size_t)r * K2 + c * 64 + clog * 8;
                const int o = ch * 16;
                load_lds16(Bbase + goff,       (char*)Th + o);
                load_lds16(Bbase + goff + 256, (char*)Tl + o);
            }
            __builtin_amdgcn_s_waitcnt(0);   // producer drains; consumers don't
            __hip_atomic_store(&ready4[c], 1, __ATOMIC_RELEASE,
                               __HIP_MEMORY_SCOPE_WORKGROUP);
        }
        return;  // producer does no epilogue
    }

    // ================= COMPUTE WAVES (w = 0..3) =================
    floatx4 acc[2][8] = {};
    const unsigned short* AhFrag = gA + (size_t)(bi * 128 + w * 32 + l16) * K2 + quad * 8;
    const unsigned short* AlFrag = AhFrag + 256;

    short8 ah[2][2], al[2][2];     // [buf][mi], prefetched one ks ahead
    #pragma unroll
    for (int mi = 0; mi < 2; ++mi){
        ah[0][mi] = *(const short8*)(AhFrag + (size_t)(mi * 16) * K2);
        al[0][mi] = *(const short8*)(AlFrag + (size_t)(mi * 16) * K2);
    }
    int cur = 0;

    #pragma unroll 1
    for (int c = 0; c < 4; ++c){
        while (__hip_atomic_load(&ready4[c], __ATOMIC_ACQUIRE,
                                 __HIP_MEMORY_SCOPE_WORKGROUP) == 0)
            __builtin_amdgcn_s_sleep(1);
        const unsigned short* Th = Bh[c & 1];
        const unsigned short* Tl = Bl[c & 1];

        #pragma unroll
        for (int ks = 0; ks < 2; ++ks){
            // prefetch A frags for next (c,ks) — registers, barrier-free
            const int t = c * 2 + ks;
            if (t < 7){
                const size_t noff = (size_t)(t + 1) * 32;
                #pragma unroll
                for (int mi = 0; mi < 2; ++mi){
                    ah[cur ^ 1][mi] = *(const short8*)(AhFrag + (size_t)(mi * 16) * K2 + noff);
                    al[cur ^ 1][mi] = *(const short8*)(AlFrag + (size_t)(mi * 16) * K2 + noff);
                }
            }

            const int co = ((ks * 4 + quad) ^ sw) * 8;
            #pragma unroll
            for (int h = 0; h < 2; ++h){
                short8 bh4[4], bl4[4];
                #pragma unroll
                for (int j = 0; j < 4; ++j){
                    bh4[j] = *(const short8*)&Th[((h * 4 + j) * 16 + l16) * 64 + co];
                    bl4[j] = *(const short8*)&Tl[((h * 4 + j) * 16 + l16) * 64 + co];
                }
                // pass 1: Ah*Bh
                #pragma unroll
                for (int j = 0; j < 4; ++j){
                    acc[0][h*4+j] = __builtin_amdgcn_mfma_f32_16x16x32_bf16(ah[cur][0], bh4[j], acc[0][h*4+j], 0, 0, 0);
                    acc[1][h*4+j] = __builtin_amdgcn_mfma_f32_16x16x32_bf16(ah[cur][1], bh4[j], acc[1][h*4+j], 0, 0, 0);
                }
                // pass 2: Al*Bh
                #pragma unroll
                for (int j = 0; j < 4; ++j){
                    acc[0][h*4+j] = __builtin_amdgcn_mfma_f32_16x16x32_bf16(al[cur][0], bh4[j], acc[0][h*4+j], 0, 0, 0);
                    acc[1][h*4+j] = __builtin_amdgcn_mfma_f32_16x16x32_bf16(al[cur][1], bh4[j], acc[1][h*4+j], 0, 0, 0);
                }
                // pass 3: Ah*Bl
                #pragma unroll
                for (int j = 0; j < 4; ++j){
                    acc[0][h*4+j] = __builtin_amdgcn_mfma_f32_16x16x32_bf16(ah[cur][0], bl4[j], acc[0][h*4+j], 0, 0, 0);
                    acc[1][h*4+j] = __builtin_amdgcn_mfma_f32_16x16x32_bf16(ah[cur][1], bl4[j], acc[1][h*4+j], 0, 0, 0);
                }
            }
            cur ^= 1;
        }
        // all LDS reads of this buffer are complete (their values fed MFMAs)
        if (lane == 0)
            __hip_atomic_fetch_add(&consd[c], 1, __ATOMIC_RELEASE,
                                   __HIP_MEMORY_SCOPE_WORKGROUP);
    }

    // ---- fused stats epilogue ----
    // C/D layout (verified m89/m91): col = lane&15, row = quad*4 + reg.
    // acc[mi][nj]: row = w*32 + mi*16 + quad*4 + r ; col = nj*16 + l16.
    const int rowbase = bi * 128 + w * 32;
    const int colbase = bj * 128;

    // row stats: each lane holds 8 cols (nj); reduce across l16 lanes.
    #pragma unroll
    for (int mi = 0; mi < 2; ++mi){
        #pragma unroll
        for (int r = 0; r < 4; ++r){
            const int lrow = w * 32 + mi * 16 + quad * 4 + r;
            const int gi   = bi * 128 + lrow;
            const float dv = drow[lrow];
            int cnt = 0; float mx = -3.0e38f;
            #pragma unroll
            for (int nj = 0; nj < 8; ++nj){
                const float v  = acc[mi][nj][r];
                const int   gj = colbase + nj * 16 + l16;
                if (gi != gj){                 // exclude diagonal explicitly
                    cnt += (v < dv) ? 1 : 0;
                    mx = fmaxf(mx, v);
                }
            }
            #pragma unroll
            for (int m = 1; m < 16; m <<= 1){
                cnt += __shfl_xor(cnt, m, 64);
                mx   = fmaxf(mx, __shfl_xor(mx, m, 64));
            }
            if (l16 == 0){
                atomicAdd(&g_rowcnt[gi], (unsigned)cnt);
                atomicMax(&g_rowkey[gi], fkey(mx));
            }
        }
    }
    // col stats: each lane holds 8 rows (mi,r) per nj; reduce across quad lanes.
    #pragma unroll
    for (int nj = 0; nj < 8; ++nj){
        const int lcol = nj * 16 + l16;
        const int gj   = bj * 128 + lcol;
        const float dv = dcol[lcol];
        int cnt = 0; float mx = -3.0e38f;
        #pragma unroll
        for (int mi = 0; mi < 2; ++mi){
            #pragma unroll
            for (int r = 0; r < 4; ++r){
                const float v  = acc[mi][nj][r];
                const int   gi = rowbase + mi * 16 + quad * 4 + r;
                if (gi != gj){
                    cnt += (v < dv) ? 1 : 0;
                    mx = fmaxf(mx, v);
                }
            }
        }
        #pragma unroll
        for (int m = 16; m < 64; m <<= 1){
            cnt += __shfl_xor(cnt, m, 64);
            mx   = fmaxf(mx, __shfl_xor(mx, m, 64));
        }
        if (quad == 0){
            atomicAdd(&g_colcnt[gj], (unsigned)cnt);
            atomicMax(&g_colkey[gj], fkey(mx));
        }
    }
}

__global__ __launch_bounds__(256) void finalize_kernel(float* __restrict__ out){
    __shared__ double red[256];
    double acc = 0.0;
    #pragma unroll
    for (int it = 0; it < NROWS / 256; ++it){
        const int i = it * 256 + threadIdx.x;
        const float d  = g_diag[i];
        const float cs  = fmaxf(MARGIN_F + kinv(g_rowkey[i]) - d, 0.0f) * (1.0f / (float)(g_rowcnt[i] + 1u));
        const float cim = fmaxf(MARGIN_F + kinv(g_colkey[i]) - d, 0.0f) * (1.0f / (float)(g_colcnt[i] + 1u));
        acc += (double)cs + (double)cim;
    }
    red[threadIdx.x] = acc;
    __syncthreads();
    for (int s2 = 128; s2 > 0; s2 >>= 1){
        if (threadIdx.x < s2) red[threadIdx.x] += red[threadIdx.x + s2];
        __syncthreads();
    }
    if (threadIdx.x == 0) out[0] = (float)red[0];
}

extern "C" void kernel_launch(void* const* d_in, const int* in_sizes, int n_in,
                              void* d_out, int out_size, void* d_ws, size_t ws_size,
                              hipStream_t stream){
    const float* im = (const float*)d_in[0];
    const float* s  = (const float*)d_in[1];
    float* out = (float*)d_out;

    prep_kernel<<<NROWS / 4, 256, 0, stream>>>(im, s);
    gemm_stats_kernel<<<4096, 320, 0, stream>>>();
    finalize_kernel<<<1, 256, 0, stream>>>(out);
}